// Round 1
// baseline (786.065 us; speedup 1.0000x reference)
//
#include <hip/hip_runtime.h>

// ---------------- problem dims (fixed by reference) ----------------
constexpr int BNKv = 200, Lv = 128, Dv = 1024, Ov = 1024, Rv = 50;
constexpr int Mv = BNKv * Lv;     // 25600 rows
constexpr int KP = 3072;          // split-K: [hi(1024) | lo(1024) | hi(1024)]

using u16 = unsigned short;
typedef __bf16 bf16x8 __attribute__((ext_vector_type(8)));
typedef float f32x4 __attribute__((ext_vector_type(4)));

// RNE float->bf16 (bit trick, matches v_cvt semantics for finite values)
__device__ __forceinline__ u16 f2bf(float x) {
    unsigned int u = __float_as_uint(x);
    u += 0x7fffu + ((u >> 16) & 1u);
    return (u16)(u >> 16);
}
__device__ __forceinline__ float bf2f(u16 h) {
    return __uint_as_float(((unsigned int)h) << 16);
}

// ---------------------------------------------------------------
// K1: rep (M x 1024 f32) -> A' (M x 3072 bf16, [hi|lo|hi]) + gate dots
// one block per row; 256 threads x 4 floats
// ---------------------------------------------------------------
__global__ __launch_bounds__(256) void convert_rep(
    const float* __restrict__ rep,
    const float* __restrict__ wg_in,
    const float* __restrict__ wg_self,
    u16* __restrict__ Ap,
    float* __restrict__ gout_in,
    float* __restrict__ gout_self)
{
    const int m = blockIdx.x;
    const int t = threadIdx.x;
    const float4 x  = *(const float4*)(rep + (size_t)m * Dv + t * 4);
    const float4 wi = *(const float4*)(wg_in + t * 4);
    const float4 wsf= *(const float4*)(wg_self + t * 4);

    float xs[4] = {x.x, x.y, x.z, x.w};
    u16 hb[4], lb[4];
#pragma unroll
    for (int j = 0; j < 4; ++j) {
        u16 h = f2bf(xs[j]);
        hb[j] = h;
        lb[j] = f2bf(xs[j] - bf2f(h));
    }
    ushort4 hv = make_ushort4(hb[0], hb[1], hb[2], hb[3]);
    ushort4 lv = make_ushort4(lb[0], lb[1], lb[2], lb[3]);
    u16* rowp = Ap + (size_t)m * KP;
    *(ushort4*)(rowp + t * 4)          = hv;   // hi  segment
    *(ushort4*)(rowp + 1024 + t * 4)   = lv;   // lo  segment
    *(ushort4*)(rowp + 2048 + t * 4)   = hv;   // hi  segment (pairs with Bl)

    float gi = x.x * wi.x + x.y * wi.y + x.z * wi.z + x.w * wi.w;
    float gs = x.x * wsf.x + x.y * wsf.y + x.z * wsf.z + x.w * wsf.w;
#pragma unroll
    for (int off = 32; off > 0; off >>= 1) {
        gi += __shfl_down(gi, off);
        gs += __shfl_down(gs, off);
    }
    __shared__ float ri[4], rs[4];
    if ((t & 63) == 0) { ri[t >> 6] = gi; rs[t >> 6] = gs; }
    __syncthreads();
    if (t == 0) {
        gout_in[m]   = ri[0] + ri[1] + ri[2] + ri[3];
        gout_self[m] = rs[0] + rs[1] + rs[2] + rs[3];
    }
}

// ---------------------------------------------------------------
// K2: W (1024x1024 f32) -> Bt (1024 x 3072 bf16, [Bh|Bh|Bl]), transposed
// 64x64 tiles through LDS; grid (16 kt, 16 nt, 2 weights)
// ---------------------------------------------------------------
__global__ __launch_bounds__(256) void convert_w(
    const float* __restrict__ W0, const float* __restrict__ W1,
    u16* __restrict__ B0, u16* __restrict__ B1)
{
    const float* W = blockIdx.z ? W1 : W0;
    u16* Bt = blockIdx.z ? B1 : B0;
    const int kt = blockIdx.x, nt = blockIdx.y;
    __shared__ float tile[64][65];
    const int tid = threadIdx.x;
    const int c = tid & 63, r4 = tid >> 6;
#pragma unroll 4
    for (int it = 0; it < 16; ++it) {
        int kl = it * 4 + r4;
        tile[kl][c] = W[(size_t)(kt * 64 + kl) * Ov + nt * 64 + c];
    }
    __syncthreads();
#pragma unroll 4
    for (int it = 0; it < 16; ++it) {
        int nl = it * 4 + r4;
        float v = tile[c][nl];
        u16 h = f2bf(v);
        u16 lo = f2bf(v - bf2f(h));
        size_t base = (size_t)(nt * 64 + nl) * KP + kt * 64 + c;
        Bt[base]        = h;
        Bt[base + 1024] = h;
        Bt[base + 2048] = lo;
    }
}

// ---------------------------------------------------------------
// K3/K4: gemm_bt, m97 structure. 128x128 tile, BK=64, 4 waves (2x2),
// each wave 4x4 frags of 16x16x32 bf16 MFMA, global_load_lds width 16.
// FUSED: epilogue gathers P[idx[m]] + b_in[lab[m]], gates, relu -> out
// ---------------------------------------------------------------
template <bool FUSED>
__global__ __launch_bounds__(256) void gemm_bt(
    const u16* __restrict__ A, const u16* __restrict__ Bt,
    float* __restrict__ P,            // !FUSED: output; FUSED: gather input
    float* __restrict__ out,
    const float* __restrict__ g_in, const float* __restrict__ g_self,
    const int* __restrict__ arc, const int* __restrict__ lab,
    const float* __restrict__ am_in, const float* __restrict__ am_loop,
    const float* __restrict__ maskBL,
    const float* __restrict__ b_in, const float* __restrict__ b_gate_in)
{
    __shared__ u16 As[128 * 64];
    __shared__ u16 Bs[128 * 64];
    __shared__ float w0s[128], w1s[128];
    __shared__ int pidx[128], plab[128];

    const int tid = threadIdx.x;
    const int l = tid & 63;
    const int w = tid >> 6;
    const int gm0 = (blockIdx.x >> 3) * 128;
    const int gn0 = (blockIdx.x & 7) * 128;
    const int wm = (w >> 1) * 64;
    const int wn = (w & 1) * 64;

    if constexpr (FUSED) {
        if (tid < 128) {
            const int m = gm0 + tid;
            const int gidx = arc[2 * m] * Lv + arc[2 * m + 1];
            const int lb = lab[m];
            const float am = am_in[m], lp = am_loop[m], mk = maskBL[m];
            const float gi = g_in[gidx] + b_gate_in[lb];
            const float gs = g_self[m];
            const float s_i = 1.f / (1.f + expf(-gi));
            const float s_s = 1.f / (1.f + expf(-gs));
            // relu(x)*mask == relu(x*mask) for mask in {0,1}: fold mask in.
            w0s[tid] = am * am * s_i * mk;
            w1s[tid] = lp * lp * s_s * mk;
            pidx[tid] = gidx;
            plab[tid] = lb;
        }
    }

    f32x4 acc[4][4];
#pragma unroll
    for (int i = 0; i < 4; ++i)
#pragma unroll
        for (int j = 0; j < 4; ++j) acc[i][j] = (f32x4){0.f, 0.f, 0.f, 0.f};

    const int subrow = l >> 3;         // 0..7 within 8-row chunk
    const int kkoff = (l & 7) * 8;     // 0..56, 8 bf16 = 16B per lane
    const int lrow = l & 15;
    const int lk = (l >> 4) * 8;

    for (int kt = 0; kt < KP / 64; ++kt) {
        const int kb = kt * 64;
#pragma unroll
        for (int i = 0; i < 4; ++i) {
            const int chunk = i * 4 + w;  // wave-uniform
            const u16* ga = A + (size_t)(gm0 + chunk * 8 + subrow) * KP + kb + kkoff;
            __builtin_amdgcn_global_load_lds(
                (const __attribute__((address_space(1))) void*)ga,
                (__attribute__((address_space(3))) void*)(&As[chunk * 512]), 16, 0, 0);
        }
#pragma unroll
        for (int i = 0; i < 4; ++i) {
            const int chunk = i * 4 + w;
            const u16* gb = Bt + (size_t)(gn0 + chunk * 8 + subrow) * KP + kb + kkoff;
            __builtin_amdgcn_global_load_lds(
                (const __attribute__((address_space(1))) void*)gb,
                (__attribute__((address_space(3))) void*)(&Bs[chunk * 512]), 16, 0, 0);
        }
        __syncthreads();   // vmcnt(0) drain: LDS tiles ready
#pragma unroll
        for (int ks = 0; ks < 2; ++ks) {
            const int k0 = ks * 32 + lk;
            bf16x8 af[4], bfr[4];
#pragma unroll
            for (int mi = 0; mi < 4; ++mi)
                af[mi] = *(const bf16x8*)&As[(wm + mi * 16 + lrow) * 64 + k0];
#pragma unroll
            for (int ni = 0; ni < 4; ++ni)
                bfr[ni] = *(const bf16x8*)&Bs[(wn + ni * 16 + lrow) * 64 + k0];
#pragma unroll
            for (int mi = 0; mi < 4; ++mi)
#pragma unroll
                for (int ni = 0; ni < 4; ++ni)
                    acc[mi][ni] = __builtin_amdgcn_mfma_f32_16x16x32_bf16(
                        af[mi], bfr[ni], acc[mi][ni], 0, 0, 0);
        }
        __syncthreads();   // compute done before next stage overwrites LDS
    }

    const int orow = (l >> 4) * 4;   // C/D: row = (lane>>4)*4 + reg
    const int ocol = l & 15;         //      col = lane&15
    if constexpr (!FUSED) {
#pragma unroll
        for (int mi = 0; mi < 4; ++mi)
#pragma unroll
            for (int ni = 0; ni < 4; ++ni) {
                const int col = gn0 + wn + ni * 16 + ocol;
#pragma unroll
                for (int r = 0; r < 4; ++r) {
                    const int row = gm0 + wm + mi * 16 + orow + r;
                    P[(size_t)row * Ov + col] = acc[mi][ni][r];
                }
            }
    } else {
#pragma unroll
        for (int mi = 0; mi < 4; ++mi) {
#pragma unroll
            for (int r = 0; r < 4; ++r) {
                const int rloc = wm + mi * 16 + orow + r;
                const float w0 = w0s[rloc], w1 = w1s[rloc];
                const size_t prow = (size_t)pidx[rloc] * Ov;
                const size_t brow = (size_t)plab[rloc] * Ov;
                const size_t mrow = (size_t)(gm0 + rloc) * Ov;
#pragma unroll
                for (int ni = 0; ni < 4; ++ni) {
                    const int col = gn0 + wn + ni * 16 + ocol;
                    const float pin = P[prow + col] + b_in[brow + col];
                    const float v = pin * w0 + acc[mi][ni][r] * w1;
                    out[mrow + col] = fmaxf(v, 0.f);
                }
            }
        }
    }
}

// ---------------- workspace layout ----------------
constexpr size_t SZ_A  = (size_t)Mv * KP * 2;          // 157,286,400
constexpr size_t SZ_B  = (size_t)Ov * KP * 2;          //   6,291,456
constexpr size_t OFF_A  = 0;
constexpr size_t OFF_B1 = OFF_A + SZ_A;
constexpr size_t OFF_B2 = OFF_B1 + SZ_B;
constexpr size_t OFF_GI = OFF_B2 + SZ_B;
constexpr size_t OFF_GS = OFF_GI + (size_t)Mv * 4;
constexpr size_t OFF_P  = OFF_GS + (size_t)Mv * 4;     // + 104,857,600

extern "C" void kernel_launch(void* const* d_in, const int* in_sizes, int n_in,
                              void* d_out, int out_size, void* d_ws, size_t ws_size,
                              hipStream_t stream) {
    const float* rep       = (const float*)d_in[0];
    const int*   arc       = (const int*)d_in[1];
    const int*   lab       = (const int*)d_in[2];
    const float* am_in     = (const float*)d_in[3];
    const float* am_loop   = (const float*)d_in[4];
    const float* maskBL    = (const float*)d_in[5];
    const float* W_in      = (const float*)d_in[6];
    const float* b_in      = (const float*)d_in[7];
    const float* W_gate_in = (const float*)d_in[8];
    const float* b_gate_in = (const float*)d_in[9];
    const float* W_self    = (const float*)d_in[10];
    const float* W_gate_self = (const float*)d_in[11];
    float* out = (float*)d_out;
    char* ws = (char*)d_ws;

    u16*   Ap  = (u16*)(ws + OFF_A);
    u16*   Bt1 = (u16*)(ws + OFF_B1);
    u16*   Bt2 = (u16*)(ws + OFF_B2);
    float* gIn = (float*)(ws + OFF_GI);
    float* gSf = (float*)(ws + OFF_GS);
    float* P   = (float*)(ws + OFF_P);

    convert_rep<<<Mv, 256, 0, stream>>>(rep, W_gate_in, W_gate_self, Ap, gIn, gSf);
    convert_w<<<dim3(16, 16, 2), 256, 0, stream>>>(W_in, W_self, Bt1, Bt2);

    const int gemm_grid = (Mv / 128) * (Ov / 128);  // 1600
    gemm_bt<false><<<gemm_grid, 256, 0, stream>>>(
        Ap, Bt1, P, nullptr, nullptr, nullptr, nullptr, nullptr,
        nullptr, nullptr, nullptr, nullptr, nullptr);
    gemm_bt<true><<<gemm_grid, 256, 0, stream>>>(
        Ap, Bt2, P, out, gIn, gSf, arc, lab, am_in, am_loop, maskBL,
        b_in, b_gate_in);
}